// Round 7
// baseline (2326.106 us; speedup 1.0000x reference)
//
#include <hip/hip_runtime.h>

typedef unsigned char  u8;
typedef unsigned short u16;
typedef unsigned int   u32;
typedef short  bf16x8 __attribute__((ext_vector_type(8)));
typedef float  f32x4  __attribute__((ext_vector_type(4)));

#define T_SEQ 256
#define BATCH 1024
#define HID   128

__device__ __forceinline__ u16 f2bf(float f) {
  u32 x = __builtin_bit_cast(u32, f);
  x = x + 0x7fffu + ((x >> 16) & 1u);   // round-to-nearest-even
  return (u16)(x >> 16);
}
__device__ __forceinline__ float sigm(float x) {
  return __builtin_amdgcn_rcpf(1.0f + __expf(-x));
}
__device__ __forceinline__ float tanh_f(float x) {
  return 2.0f * __builtin_amdgcn_rcpf(1.0f + __expf(-2.0f * x)) - 1.0f;
}
// lane L <-> L^8 within each 16-lane row, on the VALU pipe (DPP row_ror:8).
__device__ __forceinline__ float dpp_xor8(float v) {
  int i = __builtin_bit_cast(int, v);
  i = __builtin_amdgcn_update_dpp(0, i, 0x128 /*row_ror:8*/, 0xf, 0xf, true);
  return __builtin_bit_cast(float, i);
}
// LDS-only barrier (R9): hbuf exchange needs lgkmcnt(0) only.
__device__ __forceinline__ void lds_barrier() {
  __builtin_amdgcn_sched_barrier(0);
  asm volatile("s_waitcnt lgkmcnt(0)" ::: "memory");
  __builtin_amdgcn_sched_barrier(0);
  __builtin_amdgcn_s_barrier();
}
// runtime row-select from f32x4 (3 v_cndmask; quad is a per-lane value)
__device__ __forceinline__ float sel_row(const f32x4& a, int q1, int q2) {
  float lo = q1 ? a[1] : a[0];
  float hi2 = q1 ? a[3] : a[2];
  return q2 ? hi2 : lo;
}

// ---------------------------------------------------------------------------
// Convert x_in fp32 -> bf16 (4/thread) + zero the 256 u8 producer flags.
// ---------------------------------------------------------------------------
__global__ void conv_x_kernel(const float* __restrict__ x_in, u16* __restrict__ xb,
                              u32* __restrict__ flags) {
  if (blockIdx.x == 0 && threadIdx.x < 64) flags[threadIdx.x] = 0;  // 64 u32 = 256 u8
  int i = (blockIdx.x * blockDim.x + threadIdx.x) * 4;
  float4 v = *(const float4*)(x_in + i);
  u32 lo = (u32)f2bf(v.x) | ((u32)f2bf(v.y) << 16);
  u32 hi = (u32)f2bf(v.z) | ((u32)f2bf(v.w) << 16);
  *(u32*)(xb + i) = lo;
  *(u32*)(xb + i + 2) = hi;
}

// ---------------------------------------------------------------------------
// Prep (PERMUTED gate layout — compute-validated R2-R4). Unchanged.
// ---------------------------------------------------------------------------
__global__ void prep_kernel(const float* __restrict__ pre_w, const float* __restrict__ pre_b,
                            const float* __restrict__ w_ih0, const float* __restrict__ w_hh0,
                            const float* __restrict__ b_ih0, const float* __restrict__ b_hh0,
                            const float* __restrict__ w_ih1, const float* __restrict__ w_hh1,
                            const float* __restrict__ b_ih1, const float* __restrict__ b_hh1,
                            u16* __restrict__ WcP, u16* __restrict__ WhhP0,
                            u16* __restrict__ WihP1, u16* __restrict__ WhhP1,
                            float* __restrict__ bias0, float* __restrict__ bias1) {
  const int TOT = 230400;
  for (int idx = blockIdx.x * blockDim.x + threadIdx.x; idx < TOT;
       idx += gridDim.x * blockDim.x) {
    if (idx < 32768) {                       // WcP (KK=2)
      int e = idx & 7, lane = (idx >> 3) & 63, kk = (idx >> 9) & 1,
          tile = (idx >> 10) & 1, n = idx >> 11;
      int col = lane & 15, quad = lane >> 4;
      int r = (tile * 2 + (col >> 3)) * 128 + n * 8 + (col & 7);
      int k = kk * 32 + quad * 8 + e;
      float s = 0.f;
      for (int h = 0; h < 128; ++h)
        s += w_ih0[r * 128 + h] * pre_w[h * 64 + k];
      WcP[idx] = f2bf(s);
    } else if (idx < 33280) {                // bias0 permuted (fp32)
      int p = idx - 32768;
      int col = p & 15, tile = (p >> 4) & 1, n = p >> 5;
      int r = (tile * 2 + (col >> 3)) * 128 + n * 8 + (col & 7);
      float s = b_ih0[r] + b_hh0[r];
      for (int h = 0; h < 128; ++h)
        s += w_ih0[r * 128 + h] * pre_b[h];
      bias0[p] = s;
    } else if (idx < 229888) {               // 3 permuted bf16 copies (KK=4)
      int q = idx - 33280;
      int mat = q / 65536; q = q % 65536;
      int e = q & 7, lane = (q >> 3) & 63, kk = (q >> 9) & 3,
          tile = (q >> 11) & 1, n = q >> 12;
      int col = lane & 15, quad = lane >> 4;
      int r = (tile * 2 + (col >> 3)) * 128 + n * 8 + (col & 7);
      int k = kk * 32 + quad * 8 + e;
      const float* src = mat == 0 ? w_hh0 : (mat == 1 ? w_ih1 : w_hh1);
      u16* dst = mat == 0 ? WhhP0 : (mat == 1 ? WihP1 : WhhP1);
      dst[q] = f2bf(src[r * 128 + k]);
    } else {                                 // bias1 permuted (fp32)
      int p = idx - 229888;
      int col = p & 15, tile = (p >> 4) & 1, n = p >> 5;
      int r = (tile * 2 + (col >> 3)) * 128 + n * 8 + (col & 7);
      bias1[p] = b_ih1[r] + b_hh1[r];
    }
  }
}

// ---------------------------------------------------------------------------
// R14: TWO INDEPENDENT WGs PER CU. 512 WGs x 512 thr (8 waves), 4 batch rows
// per WG, A-operand dup4 (rows 4..15 duplicate 0..3 via col&3).
//  * Per-CU wave count unchanged (16) but split into 2 phase-independent WGs:
//    one WG's barrier convoy / LDS phase overlaps the other's compute.
//  * Each wave owns 16 jcols -> 4 weight tiles tau: n=2*wave+(tau&1),
//    t2=tau>>1. With dup4 every lane holds ALL 4 rows of its D-column, so
//    lane (col,quad) owns cell (row=quad, jcol=(2*wave+hi)*8+(col&7));
//    runtime row-select via 3 cndmask; same validated col^8 DPP swap gives
//    the partner-half gates (f,o for lo; i,g for hi).
//  * LDS h-tile [4][128] bf16, chunk-swizzled: chunk' = chunk ^ (row<<2)
//    (write/read matched; 2-way bank alias max).
//  * Flags: u8 GROUP counts (4-step groups, max 64) in the same 256 B slot.
//  * R8 relaxed agent stores/flags, R9 lds_barrier, R13 merged poll kept.
// ---------------------------------------------------------------------------
template <int KKI, bool PROD>
__device__ __forceinline__ void scan_role(
    const u16* __restrict__ xsrc, const u16* __restrict__ WihF,
    const u16* __restrict__ WhhF, const float* __restrict__ biasP,
    const float* __restrict__ h0_in, const float* __restrict__ c0_in,
    u16* __restrict__ y_out, u8* flag, float* __restrict__ dout,
    const float* __restrict__ post_w, const float* __restrict__ post_b,
    int b0, u32 (*hbuf)[256], float (*h32)[130]) {
  constexpr int KIN = KKI * 32;
  constexpr int LAYER = PROD ? 0 : 1;
  const int tid = threadIdx.x, wave = tid >> 6, lane = tid & 63;
  const int col = lane & 15, quad = lane >> 4;
  const int hi = col >> 3, c7 = col & 7;
  const int q1 = quad & 1, q2 = quad & 2;
  const int n = 2 * wave + hi;            // 8-jcol group (0..15)
  const int jcol = n * 8 + c7;            // this lane's h column
  const int row = quad;                   // this lane's batch row (0..3)

  bf16x8 wih[4][KKI], whh[4][4];
  float bias[4];
#pragma unroll
  for (int tau = 0; tau < 4; ++tau) {
    int nt = 2 * wave + (tau & 1), t2 = tau >> 1;
#pragma unroll
    for (int kk = 0; kk < KKI; ++kk)
      wih[tau][kk] = *(const bf16x8*)(WihF + (((nt * 2 + t2) * KKI + kk) * 64 + lane) * 8);
#pragma unroll
    for (int kk = 0; kk < 4; ++kk)
      whh[tau][kk] = *(const bf16x8*)(WhhF + (((nt * 2 + t2) * 4 + kk) * 64 + lane) * 8);
    bias[tau] = biasP[nt * 32 + t2 * 16 + col];
  }

  float cst = c0_in[(LAYER * BATCH + b0 + row) * HID + jcol];
  float hf  = h0_in[(LAYER * BATCH + b0 + row) * HID + jcol];

  if (wave < 4) {  // init hbuf[0] rows 0..3 = h0 (chunk-swizzled bf16)
    const float* src = h0_in + (LAYER * BATCH + b0 + wave) * HID + lane * 2;
    u32 v = (u32)f2bf(src[0]) | ((u32)f2bf(src[1]) << 16);
    hbuf[0][wave * 64 + ((((lane >> 2) ^ (wave << 2))) << 2) + (lane & 3)] = v;
  }

  if (!PROD) {  // initial sync: producer >= 2 groups (8 steps) ahead
    if (tid == 0) {
      while (__hip_atomic_load(flag, __ATOMIC_RELAXED, __HIP_MEMORY_SCOPE_AGENT) < (u8)2)
        __builtin_amdgcn_s_sleep(4);
    }
  }
  __syncthreads();

  const u16* xrow = xsrc + (b0 + (col & 3)) * KIN;  // dup4: lanes share rows mod 4
  bf16x8 ax[KKI], ah[4];
#pragma unroll
  for (int kk = 0; kk < KKI; ++kk)   // preload x(0)
    ax[kk] = *(const bf16x8*)(xrow + kk * 32 + quad * 8);

  for (int t = 0; t < T_SEQ; ++t) {
    const int cb = t & 1, nb = (t + 1) & 1;
#pragma unroll
    for (int kk = 0; kk < 4; ++kk)    // h rows (col&3); chunk' = chunk^(row<<2)
      ah[kk] = *(const bf16x8*)((const char*)&hbuf[cb][0] + (col & 3) * 256 +
                                (((kk * 4 + quad) ^ ((col & 3) << 2)) << 4));
    f32x4 acc[4];
#pragma unroll
    for (int tau = 0; tau < 4; ++tau)
      acc[tau] = (f32x4){bias[tau], bias[tau], bias[tau], bias[tau]};
#pragma unroll
    for (int kk = 0; kk < KKI; ++kk)
#pragma unroll
      for (int tau = 0; tau < 4; ++tau)
        acc[tau] = __builtin_amdgcn_mfma_f32_16x16x32_bf16(ax[kk], wih[tau][kk], acc[tau], 0, 0, 0);
    if (t + 1 < T_SEQ) {   // in-place prefetch x(t+1); flag window covers it
      const u16* xn = xrow + BATCH * KIN;
#pragma unroll
      for (int kk = 0; kk < KKI; ++kk)
        ax[kk] = *(const bf16x8*)(xn + kk * 32 + quad * 8);
    }
#pragma unroll
    for (int kk = 0; kk < 4; ++kk)
#pragma unroll
      for (int tau = 0; tau < 4; ++tau)
        acc[tau] = __builtin_amdgcn_mfma_f32_16x16x32_bf16(ah[kk], whh[tau][kk], acc[tau], 0, 0, 0);
    // gate phase: row-select (3 cndmask each) + validated col^8 DPP swap
    {
      float v0 = sel_row(acc[0], q1, q2);   // tile (n even, i|f), row=quad, own col
      float v1 = sel_row(acc[1], q1, q2);   // (n odd, i|f)
      float v2 = sel_row(acc[2], q1, q2);   // (n even, g|o)
      float v3 = sel_row(acc[3], q1, q2);   // (n odd, g|o)
      float send0 = hi ? v0 : v1;
      float recv0 = dpp_xor8(send0);
      float iv = hi ? recv0 : v0;           // lo: own i[jlo]; hi: partner i[jhi]
      float fv = hi ? v1 : recv0;           // hi: own f[jhi]; lo: partner f[jlo]
      float send1 = hi ? v2 : v3;
      float recv1 = dpp_xor8(send1);
      float gv = hi ? recv1 : v2;
      float ov = hi ? v3 : recv1;
      float si = sigm(iv), sf = sigm(fv), tg = tanh_f(gv), so = sigm(ov);
      float cn = sf * cst + si * tg;
      cst = cn;
      hf = so * tanh_f(cn);
      // h[row=quad][jcol]: chunk = n, chunk' = n ^ (quad<<2)
      *(u16*)((char*)&hbuf[nb][0] + quad * 256 + ((n ^ (quad << 2)) << 4) + c7 * 2) =
          f2bf(hf);
    }
    if (PROD && (t & 3) == 3) {
      __syncthreads();   // full drain: all waves' y0 stores of steps <= t-1 done
      if (wave < 4) {
        u32 v = hbuf[nb][wave * 64 + ((((lane >> 2) ^ (wave << 2))) << 2) + (lane & 3)];
        __hip_atomic_store((u32*)(y_out + (t * BATCH + b0 + wave) * HID + lane * 2), v,
                           __ATOMIC_RELAXED, __HIP_MEMORY_SCOPE_AGENT);
      }
      if (tid == 0)
        __hip_atomic_store(flag, (u8)((t >> 2) + 1), __ATOMIC_RELAXED, __HIP_MEMORY_SCOPE_AGENT);
    } else {
      // merged consumer poll (R13) — wait BEFORE the single step barrier
      if (!PROD && (t & 3) == 3 && t + 1 < T_SEQ) {
        if (tid == 0) {
          int g = (t + 9) >> 2;
          u8 tgt = (u8)(g > 64 ? 64 : g);
          while (__hip_atomic_load(flag, __ATOMIC_RELAXED, __HIP_MEMORY_SCOPE_AGENT) < tgt)
            __builtin_amdgcn_s_sleep(4);
        }
      }
      lds_barrier();     // lgkmcnt-only, global ops ride across
      if (PROD && wave < 4) {
        u32 v = hbuf[nb][wave * 64 + ((((lane >> 2) ^ (wave << 2))) << 2) + (lane & 3)];
        __hip_atomic_store((u32*)(y_out + (t * BATCH + b0 + wave) * HID + lane * 2), v,
                           __ATOMIC_RELAXED, __HIP_MEMORY_SCOPE_AGENT);
      }
    }
    xrow += BATCH * KIN;
  }
  if (PROD) {
    __syncthreads();   // drain final y stores
    if (tid == 0)
      __hip_atomic_store(flag, (u8)64, __ATOMIC_RELAXED, __HIP_MEMORY_SCOPE_AGENT);
  }

  // ---- finals from fp32 registers (one cell per lane) ----
  dout[BATCH + LAYER * (BATCH * HID) + (b0 + row) * HID + jcol] = hf;
  dout[BATCH + 2 * BATCH * HID + LAYER * (BATCH * HID) + (b0 + row) * HID + jcol] = cst;

  if (!PROD) {  // pred via fp32 LDS stage (4 rows)
    h32[row][jcol] = hf;
    __syncthreads();
    if (wave < 4) {
      float a0 = fmaxf(h32[wave][2 * lane], 0.f);
      float a1 = fmaxf(h32[wave][2 * lane + 1], 0.f);
      float p = a0 * post_w[2 * lane] + a1 * post_w[2 * lane + 1];
#pragma unroll
      for (int off = 32; off > 0; off >>= 1) p += __shfl_down(p, off, 64);
      if (lane == 0) dout[b0 + wave] = p + post_b[0];
    }
  }
}

__global__ __launch_bounds__(512, 4) void lstm_fused(
    const u16* __restrict__ xb,
    const u16* __restrict__ WcP, const u16* __restrict__ WhhP0,
    const float* __restrict__ bias0,
    const u16* __restrict__ WihP1, const u16* __restrict__ WhhP1,
    const float* __restrict__ bias1,
    const float* __restrict__ h0_in, const float* __restrict__ c0_in,
    u16* __restrict__ y0, u8* __restrict__ flags, float* __restrict__ dout,
    const float* __restrict__ post_w, const float* __restrict__ post_b) {
  __shared__ __align__(16) u32 hbuf[2][256];
  __shared__ float h32[4][130];
  const int role = blockIdx.x >> 8;      // pairs (L0 b, L1 b) same XCD (256%8==0)
  const int blk = blockIdx.x & 255;
  const int b0 = blk * 4;
  if (role == 0)
    scan_role<2, true>(xb, WcP, WhhP0, bias0, h0_in, c0_in, y0, &flags[blk], dout,
                       post_w, post_b, b0, hbuf, h32);
  else
    scan_role<4, false>(y0, WihP1, WhhP1, bias1, h0_in, c0_in, y0, &flags[blk], dout,
                        post_w, post_b, b0, hbuf, h32);
}

extern "C" void kernel_launch(void* const* d_in, const int* in_sizes, int n_in,
                              void* d_out, int out_size, void* d_ws, size_t ws_size,
                              hipStream_t stream) {
  const float* x_in  = (const float*)d_in[0];
  const float* h0    = (const float*)d_in[1];
  const float* c0    = (const float*)d_in[2];
  const float* pre_w = (const float*)d_in[3];
  const float* pre_b = (const float*)d_in[4];
  const float* w_ih0 = (const float*)d_in[5];
  const float* w_hh0 = (const float*)d_in[6];
  const float* b_ih0 = (const float*)d_in[7];
  const float* b_hh0 = (const float*)d_in[8];
  const float* w_ih1 = (const float*)d_in[9];
  const float* w_hh1 = (const float*)d_in[10];
  const float* b_ih1 = (const float*)d_in[11];
  const float* b_hh1 = (const float*)d_in[12];
  const float* post_w = (const float*)d_in[13];
  const float* post_b = (const float*)d_in[14];
  float* out = (float*)d_out;
  char* ws = (char*)d_ws;

  u16*   WcP   = (u16*)(ws + 0);        // 65536 B
  u16*   WhhP0 = (u16*)(ws + 65536);    // 131072 B
  u16*   WihP1 = (u16*)(ws + 196608);   // 131072 B
  u16*   WhhP1 = (u16*)(ws + 327680);   // 131072 B
  float* bias0 = (float*)(ws + 458752); // 2048 B
  float* bias1 = (float*)(ws + 460800); // 2048 B
  u8*    flags = (u8*)(ws + 462848);    // 256 B (256 x u8 group counts)
  u16*   xb    = (u16*)(ws + 463104);   // 33554432 B
  u16*   y0    = (u16*)(ws + 34017536); // 67108864 B

  conv_x_kernel<<<dim3(16384), dim3(256), 0, stream>>>(x_in, xb, (u32*)flags);
  prep_kernel<<<dim3(256), dim3(256), 0, stream>>>(
      pre_w, pre_b, w_ih0, w_hh0, b_ih0, b_hh0, w_ih1, w_hh1, b_ih1, b_hh1,
      WcP, WhhP0, WihP1, WhhP1, bias0, bias1);
  lstm_fused<<<dim3(512), dim3(512), 0, stream>>>(
      xb, WcP, WhhP0, bias0, WihP1, WhhP1, bias1, h0, c0, y0, flags, out,
      post_w, post_b);
}

// Round 8
// 591.724 us; speedup vs baseline: 3.9311x; 3.9311x over previous
//
#include <hip/hip_runtime.h>

typedef unsigned short u16;
typedef unsigned int   u32;
typedef short  bf16x8 __attribute__((ext_vector_type(8)));
typedef float  f32x4  __attribute__((ext_vector_type(4)));

#define T_SEQ 256
#define BATCH 1024
#define HID   128

__device__ __forceinline__ u16 f2bf(float f) {
  u32 x = __builtin_bit_cast(u32, f);
  x = x + 0x7fffu + ((x >> 16) & 1u);   // round-to-nearest-even
  return (u16)(x >> 16);
}
__device__ __forceinline__ float sigm(float x) {
  return __builtin_amdgcn_rcpf(1.0f + __expf(-x));
}
__device__ __forceinline__ float tanh_f(float x) {
  return 2.0f * __builtin_amdgcn_rcpf(1.0f + __expf(-2.0f * x)) - 1.0f;
}
// lane L <-> L^8 within each 16-lane row, on the VALU pipe (DPP row_ror:8).
__device__ __forceinline__ float dpp_xor8(float v) {
  int i = __builtin_bit_cast(int, v);
  i = __builtin_amdgcn_update_dpp(0, i, 0x128 /*row_ror:8*/, 0xf, 0xf, true);
  return __builtin_bit_cast(float, i);
}
// LDS-only barrier (R9): hbuf exchange needs lgkmcnt(0) only.
__device__ __forceinline__ void lds_barrier() {
  __builtin_amdgcn_sched_barrier(0);
  asm volatile("s_waitcnt lgkmcnt(0)" ::: "memory");
  __builtin_amdgcn_sched_barrier(0);
  __builtin_amdgcn_s_barrier();
}

// ---------------------------------------------------------------------------
// Convert x_in fp32 -> bf16 (4/thread) + zero the 128 u16 producer flags.
// ---------------------------------------------------------------------------
__global__ void conv_x_kernel(const float* __restrict__ x_in, u16* __restrict__ xb,
                              u32* __restrict__ flags) {
  if (blockIdx.x == 0 && threadIdx.x < 64) flags[threadIdx.x] = 0;  // 64 u32 = 128 u16
  int i = (blockIdx.x * blockDim.x + threadIdx.x) * 4;
  float4 v = *(const float4*)(x_in + i);
  u32 lo = (u32)f2bf(v.x) | ((u32)f2bf(v.y) << 16);
  u32 hi = (u32)f2bf(v.z) | ((u32)f2bf(v.w) << 16);
  *(u32*)(xb + i) = lo;
  *(u32*)(xb + i + 2) = hi;
}

// ---------------------------------------------------------------------------
// Prep (PERMUTED gate layout — compute-validated R2-R4). Unchanged.
// ---------------------------------------------------------------------------
__global__ void prep_kernel(const float* __restrict__ pre_w, const float* __restrict__ pre_b,
                            const float* __restrict__ w_ih0, const float* __restrict__ w_hh0,
                            const float* __restrict__ b_ih0, const float* __restrict__ b_hh0,
                            const float* __restrict__ w_ih1, const float* __restrict__ w_hh1,
                            const float* __restrict__ b_ih1, const float* __restrict__ b_hh1,
                            u16* __restrict__ WcP, u16* __restrict__ WhhP0,
                            u16* __restrict__ WihP1, u16* __restrict__ WhhP1,
                            float* __restrict__ bias0, float* __restrict__ bias1) {
  const int TOT = 230400;
  for (int idx = blockIdx.x * blockDim.x + threadIdx.x; idx < TOT;
       idx += gridDim.x * blockDim.x) {
    if (idx < 32768) {                       // WcP (KK=2)
      int e = idx & 7, lane = (idx >> 3) & 63, kk = (idx >> 9) & 1,
          tile = (idx >> 10) & 1, n = idx >> 11;
      int col = lane & 15, quad = lane >> 4;
      int r = (tile * 2 + (col >> 3)) * 128 + n * 8 + (col & 7);
      int k = kk * 32 + quad * 8 + e;
      float s = 0.f;
      for (int h = 0; h < 128; ++h)
        s += w_ih0[r * 128 + h] * pre_w[h * 64 + k];
      WcP[idx] = f2bf(s);
    } else if (idx < 33280) {                // bias0 permuted (fp32)
      int p = idx - 32768;
      int col = p & 15, tile = (p >> 4) & 1, n = p >> 5;
      int r = (tile * 2 + (col >> 3)) * 128 + n * 8 + (col & 7);
      float s = b_ih0[r] + b_hh0[r];
      for (int h = 0; h < 128; ++h)
        s += w_ih0[r * 128 + h] * pre_b[h];
      bias0[p] = s;
    } else if (idx < 229888) {               // 3 permuted bf16 copies (KK=4)
      int q = idx - 33280;
      int mat = q / 65536; q = q % 65536;
      int e = q & 7, lane = (q >> 3) & 63, kk = (q >> 9) & 3,
          tile = (q >> 11) & 1, n = q >> 12;
      int col = lane & 15, quad = lane >> 4;
      int r = (tile * 2 + (col >> 3)) * 128 + n * 8 + (col & 7);
      int k = kk * 32 + quad * 8 + e;
      const float* src = mat == 0 ? w_hh0 : (mat == 1 ? w_ih1 : w_hh1);
      u16* dst = mat == 0 ? WhhP0 : (mat == 1 ? WihP1 : WhhP1);
      dst[q] = f2bf(src[r * 128 + k]);
    } else {                                 // bias1 permuted (fp32)
      int p = idx - 229888;
      int col = p & 15, tile = (p >> 4) & 1, n = p >> 5;
      int r = (tile * 2 + (col >> 3)) * 128 + n * 8 + (col & 7);
      bias1[p] = b_ih1[r] + b_hh1[r];
    }
  }
}

// ---------------------------------------------------------------------------
// R15 = exact R13 (best measured: 507 us kernel). R14's 2-WG/CU split is
// structurally dead: 4x weight tiles/wave needs ~176 regs vs the 64V+64A
// budget -> spill -> 5.6 GB scratch FETCH (108x) -> 4.2x regression.
// R13 structure: 256 WGs (128 prod + 128 cons) x 1024 thr, 8 batch rows,
// dup2 A-operand, one cell/lane, one lds_barrier/step, merged consumer poll.
//  * R8 relaxed agent-scope y0 stores + flags (no wbl2/inv)
//  * R9 lgkmcnt-only step barrier
//  * R10 full-machine split (all 256 CUs)
//  * R13 merged poll (1 barrier/step; poll rides the step barrier)
// ---------------------------------------------------------------------------
template <int KKI, bool PROD>
__device__ __forceinline__ void scan_role(
    const u16* __restrict__ xsrc, const u16* __restrict__ WihF,
    const u16* __restrict__ WhhF, const float* __restrict__ biasP,
    const float* __restrict__ h0_in, const float* __restrict__ c0_in,
    u16* __restrict__ y_out, u16* flag, float* __restrict__ dout,
    const float* __restrict__ post_w, const float* __restrict__ post_b,
    int b0, u32 (*hbuf)[512], float (*h32)[130]) {
  constexpr int KIN = KKI * 32;
  constexpr int LAYER = PROD ? 0 : 1;
  const int tid = threadIdx.x, wave = tid >> 6, lane = tid & 63;
  const int col = lane & 15, quad = lane >> 4;

  bf16x8 wih[2][KKI], whh[2][4];
#pragma unroll
  for (int t2 = 0; t2 < 2; ++t2)
#pragma unroll
    for (int kk = 0; kk < KKI; ++kk)
      wih[t2][kk] = *(const bf16x8*)(WihF + (((wave * 2 + t2) * KKI + kk) * 64 + lane) * 8);
#pragma unroll
  for (int t2 = 0; t2 < 2; ++t2)
#pragma unroll
    for (int kk = 0; kk < 4; ++kk)
      whh[t2][kk] = *(const bf16x8*)(WhhF + (((wave * 2 + t2) * 4 + kk) * 64 + lane) * 8);
  const float bias_t0 = biasP[wave * 32 + col];
  const float bias_t1 = biasP[wave * 32 + 16 + col];

  const int hi = col >> 3;
  const int rs = quad >> 1;                       // reg-pair select (0 or 1)
  const int m  = (quad & 1) * 4 + hi * 2 + rs;    // this lane's batch row (0..7)
  const int jcol = wave * 8 + (col & 7);

  float cst = c0_in[(LAYER * BATCH + b0 + m) * HID + jcol];
  float hf  = h0_in[(LAYER * BATCH + b0 + m) * HID + jcol];

  if (wave < 8) {  // init hbuf[0] rows 0..7 = h0 (swizzled bf16)
    const float* src = h0_in + (LAYER * BATCH + b0 + wave) * HID + lane * 2;
    u32 v = (u32)f2bf(src[0]) | ((u32)f2bf(src[1]) << 16);
    hbuf[0][wave * 64 + (((lane >> 2) ^ wave) << 2) + (lane & 3)] = v;
  }

  if (!PROD) {  // initial sync: producer must be >= 8 steps ahead (RELAXED poll)
    if (tid == 0) {
      while (__hip_atomic_load(flag, __ATOMIC_RELAXED, __HIP_MEMORY_SCOPE_AGENT) < (u16)8)
        __builtin_amdgcn_s_sleep(4);
    }
  }
  __syncthreads();

  const u16* xrow = xsrc + (b0 + (col & 7)) * KIN;  // lanes l, l^8 same row (dup A)
  bf16x8 ax[KKI], ah[4];
#pragma unroll
  for (int kk = 0; kk < KKI; ++kk)   // preload x(0)
    ax[kk] = *(const bf16x8*)(xrow + kk * 32 + quad * 8);

  for (int t = 0; t < T_SEQ; ++t) {
    const int cb = t & 1, nb = (t + 1) & 1;
#pragma unroll
    for (int kk = 0; kk < 4; ++kk)    // h rows (col&7): lanes l, l^8 broadcast
      ah[kk] = *(const bf16x8*)((const char*)&hbuf[cb][0] + (col & 7) * 256 +
                                (((kk * 4 + quad) ^ (col & 7)) << 4));
    f32x4 acc0 = {bias_t0, bias_t0, bias_t0, bias_t0};
    f32x4 acc1 = {bias_t1, bias_t1, bias_t1, bias_t1};
#pragma unroll
    for (int kk = 0; kk < KKI; ++kk) {
      acc0 = __builtin_amdgcn_mfma_f32_16x16x32_bf16(ax[kk], wih[0][kk], acc0, 0, 0, 0);
      acc1 = __builtin_amdgcn_mfma_f32_16x16x32_bf16(ax[kk], wih[1][kk], acc1, 0, 0, 0);
    }
    if (t + 1 < T_SEQ) {   // in-place prefetch x(t+1); flag window covers it
      const u16* xn = xrow + BATCH * KIN;
#pragma unroll
      for (int kk = 0; kk < KKI; ++kk)
        ax[kk] = *(const bf16x8*)(xn + kk * 32 + quad * 8);
    }
#pragma unroll
    for (int kk = 0; kk < 4; ++kk) {
      acc0 = __builtin_amdgcn_mfma_f32_16x16x32_bf16(ah[kk], whh[0][kk], acc0, 0, 0, 0);
      acc1 = __builtin_amdgcn_mfma_f32_16x16x32_bf16(ah[kk], whh[1][kk], acc1, 0, 0, 0);
    }
    // single-cell gate phase (validated exchange with rr := rs, one iter)
    {
      float a_lo0 = rs ? acc0[1] : acc0[0];
      float a_hi0 = rs ? acc0[3] : acc0[2];
      float a_lo1 = rs ? acc1[1] : acc1[0];
      float a_hi1 = rs ? acc1[3] : acc1[2];
      float send0 = hi ? a_lo0 : a_hi0;
      float send1 = hi ? a_lo1 : a_hi1;
      float recv0 = dpp_xor8(send0);
      float recv1 = dpp_xor8(send1);
      float keep0 = hi ? a_hi0 : a_lo0;
      float keep1 = hi ? a_hi1 : a_lo1;
      float iv = hi ? recv0 : keep0;
      float fv = hi ? keep0 : recv0;
      float gv = hi ? recv1 : keep1;
      float ov = hi ? keep1 : recv1;
      float si = sigm(iv), sf = sigm(fv), tg = tanh_f(gv), so = sigm(ov);
      float cn = sf * cst + si * tg;
      cst = cn;
      hf = so * tanh_f(cn);
      *(u16*)((char*)&hbuf[nb][0] + m * 256 + ((wave ^ m) << 4) + (col & 7) * 2) =
          f2bf(hf);
    }
    if (PROD && (t & 3) == 3) {
      __syncthreads();   // full drain: all waves' y0 stores of steps <= t-1 done
      if (wave < 8) {
        u32 v = hbuf[nb][wave * 64 + (((lane >> 2) ^ wave) << 2) + (lane & 3)];
        __hip_atomic_store((u32*)(y_out + (t * BATCH + b0 + wave) * HID + lane * 2), v,
                           __ATOMIC_RELAXED, __HIP_MEMORY_SCOPE_AGENT);
      }
      if (tid == 0)
        __hip_atomic_store(flag, (u16)(t + 1), __ATOMIC_RELAXED, __HIP_MEMORY_SCOPE_AGENT);
    } else {
      // R13: merged consumer poll — wait BEFORE the (single) step barrier.
      if (!PROD && (t & 3) == 3 && t + 1 < T_SEQ) {
        if (tid == 0) {
          int nt = t + 9;
          u16 tgt = (u16)(nt > T_SEQ ? T_SEQ : nt);
          while (__hip_atomic_load(flag, __ATOMIC_RELAXED, __HIP_MEMORY_SCOPE_AGENT) < tgt)
            __builtin_amdgcn_s_sleep(4);
        }
      }
      lds_barrier();     // lgkmcnt-only, global ops ride across
      if (PROD && wave < 8) {
        u32 v = hbuf[nb][wave * 64 + (((lane >> 2) ^ wave) << 2) + (lane & 3)];
        __hip_atomic_store((u32*)(y_out + (t * BATCH + b0 + wave) * HID + lane * 2), v,
                           __ATOMIC_RELAXED, __HIP_MEMORY_SCOPE_AGENT);
      }
    }
    xrow += BATCH * KIN;
  }
  if (PROD) {
    __syncthreads();   // drain final y stores
    if (tid == 0)
      __hip_atomic_store(flag, (u16)T_SEQ, __ATOMIC_RELAXED, __HIP_MEMORY_SCOPE_AGENT);
  }

  // ---- finals from fp32 registers (one cell per lane) ----
  dout[BATCH + LAYER * (BATCH * HID) + (b0 + m) * HID + jcol] = hf;
  dout[BATCH + 2 * BATCH * HID + LAYER * (BATCH * HID) + (b0 + m) * HID + jcol] = cst;

  if (!PROD) {  // pred via fp32 LDS stage (8 rows)
    h32[m][jcol] = hf;
    __syncthreads();
    if (wave < 8) {
      float a0 = fmaxf(h32[wave][2 * lane], 0.f);
      float a1 = fmaxf(h32[wave][2 * lane + 1], 0.f);
      float p = a0 * post_w[2 * lane] + a1 * post_w[2 * lane + 1];
#pragma unroll
      for (int off = 32; off > 0; off >>= 1) p += __shfl_down(p, off, 64);
      if (lane == 0) dout[b0 + wave] = p + post_b[0];
    }
  }
}

__global__ __launch_bounds__(1024, 4) void lstm_fused(
    const u16* __restrict__ xb,
    const u16* __restrict__ WcP, const u16* __restrict__ WhhP0,
    const float* __restrict__ bias0,
    const u16* __restrict__ WihP1, const u16* __restrict__ WhhP1,
    const float* __restrict__ bias1,
    const float* __restrict__ h0_in, const float* __restrict__ c0_in,
    u16* __restrict__ y0, u16* __restrict__ flags, float* __restrict__ dout,
    const float* __restrict__ post_w, const float* __restrict__ post_b) {
  __shared__ __align__(16) u32 hbuf[2][512];
  __shared__ float h32[8][130];
  const int role = blockIdx.x >> 7;      // pairs (L0 b, L1 b) land on same XCD (128%8==0)
  const int blk = blockIdx.x & 127;
  const int b0 = blk * 8;
  if (role == 0)
    scan_role<2, true>(xb, WcP, WhhP0, bias0, h0_in, c0_in, y0, &flags[blk], dout,
                       post_w, post_b, b0, hbuf, h32);
  else
    scan_role<4, false>(y0, WihP1, WhhP1, bias1, h0_in, c0_in, y0, &flags[blk], dout,
                        post_w, post_b, b0, hbuf, h32);
}

extern "C" void kernel_launch(void* const* d_in, const int* in_sizes, int n_in,
                              void* d_out, int out_size, void* d_ws, size_t ws_size,
                              hipStream_t stream) {
  const float* x_in  = (const float*)d_in[0];
  const float* h0    = (const float*)d_in[1];
  const float* c0    = (const float*)d_in[2];
  const float* pre_w = (const float*)d_in[3];
  const float* pre_b = (const float*)d_in[4];
  const float* w_ih0 = (const float*)d_in[5];
  const float* w_hh0 = (const float*)d_in[6];
  const float* b_ih0 = (const float*)d_in[7];
  const float* b_hh0 = (const float*)d_in[8];
  const float* w_ih1 = (const float*)d_in[9];
  const float* w_hh1 = (const float*)d_in[10];
  const float* b_ih1 = (const float*)d_in[11];
  const float* b_hh1 = (const float*)d_in[12];
  const float* post_w = (const float*)d_in[13];
  const float* post_b = (const float*)d_in[14];
  float* out = (float*)d_out;
  char* ws = (char*)d_ws;

  u16*   WcP   = (u16*)(ws + 0);        // 65536 B
  u16*   WhhP0 = (u16*)(ws + 65536);    // 131072 B
  u16*   WihP1 = (u16*)(ws + 196608);   // 131072 B
  u16*   WhhP1 = (u16*)(ws + 327680);   // 131072 B
  float* bias0 = (float*)(ws + 458752); // 2048 B
  float* bias1 = (float*)(ws + 460800); // 2048 B
  u16*   flags = (u16*)(ws + 462848);   // 256 B (128 x u16)
  u16*   xb    = (u16*)(ws + 463104);   // 33554432 B
  u16*   y0    = (u16*)(ws + 34017536); // 67108864 B

  conv_x_kernel<<<dim3(16384), dim3(256), 0, stream>>>(x_in, xb, (u32*)flags);
  prep_kernel<<<dim3(256), dim3(256), 0, stream>>>(
      pre_w, pre_b, w_ih0, w_hh0, b_ih0, b_hh0, w_ih1, w_hh1, b_ih1, b_hh1,
      WcP, WhhP0, WihP1, WhhP1, bias0, bias1);
  lstm_fused<<<dim3(256), dim3(1024), 0, stream>>>(
      xb, WcP, WhhP0, bias0, WihP1, WhhP1, bias1, h0, c0, y0, flags, out,
      post_w, post_b);
}

// Round 9
// 591.235 us; speedup vs baseline: 3.9343x; 1.0008x over previous
//
#include <hip/hip_runtime.h>

typedef unsigned short u16;
typedef unsigned int   u32;
typedef short  bf16x8 __attribute__((ext_vector_type(8)));
typedef float  f32x4  __attribute__((ext_vector_type(4)));

#define T_SEQ 256
#define BATCH 1024
#define HID   128

__device__ __forceinline__ u16 f2bf(float f) {
  u32 x = __builtin_bit_cast(u32, f);
  x = x + 0x7fffu + ((x >> 16) & 1u);   // round-to-nearest-even
  return (u16)(x >> 16);
}
__device__ __forceinline__ float sigm(float x) {
  return __builtin_amdgcn_rcpf(1.0f + __expf(-x));
}
__device__ __forceinline__ float tanh_f(float x) {
  return 2.0f * __builtin_amdgcn_rcpf(1.0f + __expf(-2.0f * x)) - 1.0f;
}
// LDS-only barrier (R9): hbuf exchange needs lgkmcnt(0) only.
__device__ __forceinline__ void lds_barrier() {
  __builtin_amdgcn_sched_barrier(0);
  asm volatile("s_waitcnt lgkmcnt(0)" ::: "memory");
  __builtin_amdgcn_sched_barrier(0);
  __builtin_amdgcn_s_barrier();
}

// ---------------------------------------------------------------------------
// Convert x_in fp32 -> bf16 (4/thread) + zero the 128 u16 producer flags.
// ---------------------------------------------------------------------------
__global__ void conv_x_kernel(const float* __restrict__ x_in, u16* __restrict__ xb,
                              u32* __restrict__ flags) {
  if (blockIdx.x == 0 && threadIdx.x < 64) flags[threadIdx.x] = 0;  // 64 u32 = 128 u16
  int i = (blockIdx.x * blockDim.x + threadIdx.x) * 4;
  float4 v = *(const float4*)(x_in + i);
  u32 lo = (u32)f2bf(v.x) | ((u32)f2bf(v.y) << 16);
  u32 hi = (u32)f2bf(v.z) | ((u32)f2bf(v.w) << 16);
  *(u32*)(xb + i) = lo;
  *(u32*)(xb + i + 2) = hi;
}

// ---------------------------------------------------------------------------
// Prep — R16 TRANSPOSED (gate-major) layout.
// Weights become the MFMA A-operand: A row p (=frag col 0..15) of tile t2 in
// jcol-group n is gate (p&3) of jcol n*8 + t2*4 + (p>>2):
//     r = (col&3)*128 + n*8 + tile*4 + (col>>2),  k = kk*32 + quad*8 + e
// Bias is gate-major f32x4 per (n, t2, quad): p = n*32+t2*16+quad*4+j,
//     r = j*128 + n*8 + t2*4 + quad.
// ---------------------------------------------------------------------------
__global__ void prep_kernel(const float* __restrict__ pre_w, const float* __restrict__ pre_b,
                            const float* __restrict__ w_ih0, const float* __restrict__ w_hh0,
                            const float* __restrict__ b_ih0, const float* __restrict__ b_hh0,
                            const float* __restrict__ w_ih1, const float* __restrict__ w_hh1,
                            const float* __restrict__ b_ih1, const float* __restrict__ b_hh1,
                            u16* __restrict__ WcP, u16* __restrict__ WhhP0,
                            u16* __restrict__ WihP1, u16* __restrict__ WhhP1,
                            float* __restrict__ bias0, float* __restrict__ bias1) {
  const int TOT = 230400;
  for (int idx = blockIdx.x * blockDim.x + threadIdx.x; idx < TOT;
       idx += gridDim.x * blockDim.x) {
    if (idx < 32768) {                       // WcP (KK=2)
      int e = idx & 7, lane = (idx >> 3) & 63, kk = (idx >> 9) & 1,
          tile = (idx >> 10) & 1, n = idx >> 11;
      int col = lane & 15, quad = lane >> 4;
      int r = (col & 3) * 128 + n * 8 + tile * 4 + (col >> 2);
      int k = kk * 32 + quad * 8 + e;
      float s = 0.f;
      for (int h = 0; h < 128; ++h)
        s += w_ih0[r * 128 + h] * pre_w[h * 64 + k];
      WcP[idx] = f2bf(s);
    } else if (idx < 33280) {                // bias0 gate-major (fp32)
      int p = idx - 32768;
      int j = p & 3, quad = (p >> 2) & 3, t2 = (p >> 4) & 1, n = p >> 5;
      int r = j * 128 + n * 8 + t2 * 4 + quad;
      float s = b_ih0[r] + b_hh0[r];
      for (int h = 0; h < 128; ++h)
        s += w_ih0[r * 128 + h] * pre_b[h];
      bias0[p] = s;
    } else if (idx < 229888) {               // 3 permuted bf16 copies (KK=4)
      int q = idx - 33280;
      int mat = q / 65536; q = q % 65536;
      int e = q & 7, lane = (q >> 3) & 63, kk = (q >> 9) & 3,
          tile = (q >> 11) & 1, n = q >> 12;
      int col = lane & 15, quad = lane >> 4;
      int r = (col & 3) * 128 + n * 8 + tile * 4 + (col >> 2);
      int k = kk * 32 + quad * 8 + e;
      const float* src = mat == 0 ? w_hh0 : (mat == 1 ? w_ih1 : w_hh1);
      u16* dst = mat == 0 ? WhhP0 : (mat == 1 ? WihP1 : WhhP1);
      dst[q] = f2bf(src[r * 128 + k]);
    } else {                                 // bias1 gate-major (fp32)
      int p = idx - 229888;
      int j = p & 3, quad = (p >> 2) & 3, t2 = (p >> 4) & 1, n = p >> 5;
      int r = j * 128 + n * 8 + t2 * 4 + quad;
      bias1[p] = b_ih1[r] + b_hh1[r];
    }
  }
}

// ---------------------------------------------------------------------------
// R16: TRANSPOSED MFMA — no gate exchange. R15/R13 structure otherwise.
//  * A = weight tiles (gate-major prep above), B = x/h (dup2 batch cols).
//    The B-frag loads are BYTE-IDENTICAL to R15's ah/ax loads.
//  * D[row=gate-perm][col=batch]: lane(col,quad)'s 4 regs of tile (col>>3)
//    are i,f,g,o of cell (jcol = wave*8+hi*4+quad, batch = col&7).
//    Gate phase = 4 cndmask (tile select) + trans. No DPP, no 12-select web.
//  * Bias via f32x4 C-init (gate-major) — same values, bit-identical math.
//  * R8 relaxed agent stores/flags, R9 lds_barrier, R10 full machine,
//    R13 merged poll all retained. hbuf layout/y0 export unchanged.
// ---------------------------------------------------------------------------
template <int KKI, bool PROD>
__device__ __forceinline__ void scan_role(
    const u16* __restrict__ xsrc, const u16* __restrict__ WihF,
    const u16* __restrict__ WhhF, const float* __restrict__ biasP,
    const float* __restrict__ h0_in, const float* __restrict__ c0_in,
    u16* __restrict__ y_out, u16* flag, float* __restrict__ dout,
    const float* __restrict__ post_w, const float* __restrict__ post_b,
    int b0, u32 (*hbuf)[512], float (*h32)[130]) {
  constexpr int KIN = KKI * 32;
  constexpr int LAYER = PROD ? 0 : 1;
  const int tid = threadIdx.x, wave = tid >> 6, lane = tid & 63;
  const int col = lane & 15, quad = lane >> 4;
  const int hi = col >> 3;
  const int mrow = col & 7;                      // this lane's batch row (0..7)
  const int jcol = wave * 8 + hi * 4 + quad;     // this lane's h column

  bf16x8 wih[2][KKI], whh[2][4];
#pragma unroll
  for (int t2 = 0; t2 < 2; ++t2)
#pragma unroll
    for (int kk = 0; kk < KKI; ++kk)
      wih[t2][kk] = *(const bf16x8*)(WihF + (((wave * 2 + t2) * KKI + kk) * 64 + lane) * 8);
#pragma unroll
  for (int t2 = 0; t2 < 2; ++t2)
#pragma unroll
    for (int kk = 0; kk < 4; ++kk)
      whh[t2][kk] = *(const bf16x8*)(WhhF + (((wave * 2 + t2) * 4 + kk) * 64 + lane) * 8);
  const f32x4 bias4_0 = *(const f32x4*)(biasP + wave * 32 + quad * 4);
  const f32x4 bias4_1 = *(const f32x4*)(biasP + wave * 32 + 16 + quad * 4);

  float cst = c0_in[(LAYER * BATCH + b0 + mrow) * HID + jcol];
  float hf  = h0_in[(LAYER * BATCH + b0 + mrow) * HID + jcol];

  if (wave < 8) {  // init hbuf[0] rows 0..7 = h0 (swizzled bf16) — unchanged
    const float* src = h0_in + (LAYER * BATCH + b0 + wave) * HID + lane * 2;
    u32 v = (u32)f2bf(src[0]) | ((u32)f2bf(src[1]) << 16);
    hbuf[0][wave * 64 + (((lane >> 2) ^ wave) << 2) + (lane & 3)] = v;
  }

  if (!PROD) {  // initial sync: producer must be >= 8 steps ahead (RELAXED poll)
    if (tid == 0) {
      while (__hip_atomic_load(flag, __ATOMIC_RELAXED, __HIP_MEMORY_SCOPE_AGENT) < (u16)8)
        __builtin_amdgcn_s_sleep(4);
    }
  }
  __syncthreads();

  const u16* xrow = xsrc + (b0 + mrow) * KIN;  // lanes l, l^8 same row (dup B cols)
  bf16x8 ax[KKI], ah[4];
#pragma unroll
  for (int kk = 0; kk < KKI; ++kk)   // preload x(0)
    ax[kk] = *(const bf16x8*)(xrow + kk * 32 + quad * 8);

  for (int t = 0; t < T_SEQ; ++t) {
    const int cb = t & 1, nb = (t + 1) & 1;
#pragma unroll
    for (int kk = 0; kk < 4; ++kk)    // h rows (mrow): lanes l, l^8 broadcast
      ah[kk] = *(const bf16x8*)((const char*)&hbuf[cb][0] + mrow * 256 +
                                (((kk * 4 + quad) ^ mrow) << 4));
    f32x4 acc0 = bias4_0;
    f32x4 acc1 = bias4_1;
#pragma unroll
    for (int kk = 0; kk < KKI; ++kk) {
      acc0 = __builtin_amdgcn_mfma_f32_16x16x32_bf16(wih[0][kk], ax[kk], acc0, 0, 0, 0);
      acc1 = __builtin_amdgcn_mfma_f32_16x16x32_bf16(wih[1][kk], ax[kk], acc1, 0, 0, 0);
    }
    if (t + 1 < T_SEQ) {   // in-place prefetch x(t+1); flag window covers it
      const u16* xn = xrow + BATCH * KIN;
#pragma unroll
      for (int kk = 0; kk < KKI; ++kk)
        ax[kk] = *(const bf16x8*)(xn + kk * 32 + quad * 8);
    }
#pragma unroll
    for (int kk = 0; kk < 4; ++kk) {
      acc0 = __builtin_amdgcn_mfma_f32_16x16x32_bf16(whh[0][kk], ah[kk], acc0, 0, 0, 0);
      acc1 = __builtin_amdgcn_mfma_f32_16x16x32_bf16(whh[1][kk], ah[kk], acc1, 0, 0, 0);
    }
    // gate phase: i,f,g,o are this lane's 4 acc regs of its tile. No exchange.
    {
      float iv = hi ? acc1[0] : acc0[0];
      float fv = hi ? acc1[1] : acc0[1];
      float gv = hi ? acc1[2] : acc0[2];
      float ov = hi ? acc1[3] : acc0[3];
      float si = sigm(iv), sf = sigm(fv), tg = tanh_f(gv), so = sigm(ov);
      float cn = sf * cst + si * tg;
      cst = cn;
      hf = so * tanh_f(cn);
      // h[mrow][jcol]: chunk = jcol>>3 = wave, swizzled ^mrow; sub = jcol&7
      *(u16*)((char*)&hbuf[nb][0] + mrow * 256 + ((wave ^ mrow) << 4) +
              (hi * 4 + quad) * 2) = f2bf(hf);
    }
    if (PROD && (t & 3) == 3) {
      __syncthreads();   // full drain: all waves' y0 stores of steps <= t-1 done
      if (wave < 8) {
        u32 v = hbuf[nb][wave * 64 + (((lane >> 2) ^ wave) << 2) + (lane & 3)];
        __hip_atomic_store((u32*)(y_out + (t * BATCH + b0 + wave) * HID + lane * 2), v,
                           __ATOMIC_RELAXED, __HIP_MEMORY_SCOPE_AGENT);
      }
      if (tid == 0)
        __hip_atomic_store(flag, (u16)(t + 1), __ATOMIC_RELAXED, __HIP_MEMORY_SCOPE_AGENT);
    } else {
      // R13: merged consumer poll — wait BEFORE the (single) step barrier.
      if (!PROD && (t & 3) == 3 && t + 1 < T_SEQ) {
        if (tid == 0) {
          int nt = t + 9;
          u16 tgt = (u16)(nt > T_SEQ ? T_SEQ : nt);
          while (__hip_atomic_load(flag, __ATOMIC_RELAXED, __HIP_MEMORY_SCOPE_AGENT) < tgt)
            __builtin_amdgcn_s_sleep(4);
        }
      }
      lds_barrier();     // lgkmcnt-only, global ops ride across
      if (PROD && wave < 8) {
        u32 v = hbuf[nb][wave * 64 + (((lane >> 2) ^ wave) << 2) + (lane & 3)];
        __hip_atomic_store((u32*)(y_out + (t * BATCH + b0 + wave) * HID + lane * 2), v,
                           __ATOMIC_RELAXED, __HIP_MEMORY_SCOPE_AGENT);
      }
    }
    xrow += BATCH * KIN;
  }
  if (PROD) {
    __syncthreads();   // drain final y stores
    if (tid == 0)
      __hip_atomic_store(flag, (u16)T_SEQ, __ATOMIC_RELAXED, __HIP_MEMORY_SCOPE_AGENT);
  }

  // ---- finals from fp32 registers (one cell per lane) ----
  dout[BATCH + LAYER * (BATCH * HID) + (b0 + mrow) * HID + jcol] = hf;
  dout[BATCH + 2 * BATCH * HID + LAYER * (BATCH * HID) + (b0 + mrow) * HID + jcol] = cst;

  if (!PROD) {  // pred via fp32 LDS stage (8 rows)
    h32[mrow][jcol] = hf;
    __syncthreads();
    if (wave < 8) {
      float a0 = fmaxf(h32[wave][2 * lane], 0.f);
      float a1 = fmaxf(h32[wave][2 * lane + 1], 0.f);
      float p = a0 * post_w[2 * lane] + a1 * post_w[2 * lane + 1];
#pragma unroll
      for (int off = 32; off > 0; off >>= 1) p += __shfl_down(p, off, 64);
      if (lane == 0) dout[b0 + wave] = p + post_b[0];
    }
  }
}

__global__ __launch_bounds__(1024, 4) void lstm_fused(
    const u16* __restrict__ xb,
    const u16* __restrict__ WcP, const u16* __restrict__ WhhP0,
    const float* __restrict__ bias0,
    const u16* __restrict__ WihP1, const u16* __restrict__ WhhP1,
    const float* __restrict__ bias1,
    const float* __restrict__ h0_in, const float* __restrict__ c0_in,
    u16* __restrict__ y0, u16* __restrict__ flags, float* __restrict__ dout,
    const float* __restrict__ post_w, const float* __restrict__ post_b) {
  __shared__ __align__(16) u32 hbuf[2][512];
  __shared__ float h32[8][130];
  const int role = blockIdx.x >> 7;      // pairs (L0 b, L1 b) land on same XCD (128%8==0)
  const int blk = blockIdx.x & 127;
  const int b0 = blk * 8;
  if (role == 0)
    scan_role<2, true>(xb, WcP, WhhP0, bias0, h0_in, c0_in, y0, &flags[blk], dout,
                       post_w, post_b, b0, hbuf, h32);
  else
    scan_role<4, false>(y0, WihP1, WhhP1, bias1, h0_in, c0_in, y0, &flags[blk], dout,
                        post_w, post_b, b0, hbuf, h32);
}

extern "C" void kernel_launch(void* const* d_in, const int* in_sizes, int n_in,
                              void* d_out, int out_size, void* d_ws, size_t ws_size,
                              hipStream_t stream) {
  const float* x_in  = (const float*)d_in[0];
  const float* h0    = (const float*)d_in[1];
  const float* c0    = (const float*)d_in[2];
  const float* pre_w = (const float*)d_in[3];
  const float* pre_b = (const float*)d_in[4];
  const float* w_ih0 = (const float*)d_in[5];
  const float* w_hh0 = (const float*)d_in[6];
  const float* b_ih0 = (const float*)d_in[7];
  const float* b_hh0 = (const float*)d_in[8];
  const float* w_ih1 = (const float*)d_in[9];
  const float* w_hh1 = (const float*)d_in[10];
  const float* b_ih1 = (const float*)d_in[11];
  const float* b_hh1 = (const float*)d_in[12];
  const float* post_w = (const float*)d_in[13];
  const float* post_b = (const float*)d_in[14];
  float* out = (float*)d_out;
  char* ws = (char*)d_ws;

  u16*   WcP   = (u16*)(ws + 0);        // 65536 B
  u16*   WhhP0 = (u16*)(ws + 65536);    // 131072 B
  u16*   WihP1 = (u16*)(ws + 196608);   // 131072 B
  u16*   WhhP1 = (u16*)(ws + 327680);   // 131072 B
  float* bias0 = (float*)(ws + 458752); // 2048 B
  float* bias1 = (float*)(ws + 460800); // 2048 B
  u16*   flags = (u16*)(ws + 462848);   // 256 B (128 x u16)
  u16*   xb    = (u16*)(ws + 463104);   // 33554432 B
  u16*   y0    = (u16*)(ws + 34017536); // 67108864 B

  conv_x_kernel<<<dim3(16384), dim3(256), 0, stream>>>(x_in, xb, (u32*)flags);
  prep_kernel<<<dim3(256), dim3(256), 0, stream>>>(
      pre_w, pre_b, w_ih0, w_hh0, b_ih0, b_hh0, w_ih1, w_hh1, b_ih1, b_hh1,
      WcP, WhhP0, WihP1, WhhP1, bias0, bias1);
  lstm_fused<<<dim3(256), dim3(1024), 0, stream>>>(
      xb, WcP, WhhP0, bias0, WihP1, WhhP1, bias1, h0, c0, y0, flags, out,
      post_w, post_b);
}